// Round 1
// baseline (1241.345 us; speedup 1.0000x reference)
//
#include <hip/hip_runtime.h>
#include <hip/hip_bf16.h>

// ---------------------------------------------------------------------------
// EnhancedRGCN (3-layer GAT), N=100000 nodes, E=3200000 edges, D=32.
// Strategy: counting-sort edges by dst into CSR (once per call), then per
// layer: dense transform kernel (h = in @ W^T, plus attention scalars a_s/a_d)
// and a fused per-node edge kernel (softmax denom pass + weighted aggregation
// pass + activation epilogue). No float atomics anywhere; no segment-max
// (softmax shift-invariance; logits bounded so fp32 exp is safe).
// ---------------------------------------------------------------------------

// ---------------- sort: histogram ----------------
__global__ void k_hist(const int* __restrict__ dst, int* __restrict__ counts, int e) {
    int i = blockIdx.x * 256 + threadIdx.x;
    if (i < e) atomicAdd(&counts[dst[i]], 1);
}

// ---------------- sort: 3-kernel exclusive scan ----------------
__global__ void k_scan1(const int* __restrict__ counts, int* __restrict__ exsc,
                        int* __restrict__ bsums, int n) {
    __shared__ int tmp[1024];
    int t = threadIdx.x;
    int gid = blockIdx.x * 1024 + t;
    int v = (gid < n) ? counts[gid] : 0;
    tmp[t] = v;
    __syncthreads();
#pragma unroll
    for (int off = 1; off < 1024; off <<= 1) {
        int add = (t >= off) ? tmp[t - off] : 0;
        __syncthreads();
        tmp[t] += add;
        __syncthreads();
    }
    if (gid < n) exsc[gid] = tmp[t] - v;   // exclusive within block
    if (t == 1023) bsums[blockIdx.x] = tmp[1023];
}

__global__ void k_scan2(int* __restrict__ bsums, int nb) {
    __shared__ int tmp[128];
    int t = threadIdx.x;
    int v = (t < nb) ? bsums[t] : 0;
    tmp[t] = v;
    __syncthreads();
#pragma unroll
    for (int off = 1; off < 128; off <<= 1) {
        int add = (t >= off) ? tmp[t - off] : 0;
        __syncthreads();
        tmp[t] += add;
        __syncthreads();
    }
    if (t < nb) bsums[t] = tmp[t] - v;     // exclusive block offsets
}

__global__ void k_scan3(const int* __restrict__ exsc, const int* __restrict__ bsums,
                        int* __restrict__ row_ptr, int n, int e) {
    int gid = blockIdx.x * 1024 + threadIdx.x;
    if (gid < n) row_ptr[gid] = exsc[gid] + bsums[blockIdx.x];
    if (gid == 0) row_ptr[n] = e;
}

// ---------------- sort: scatter src ids into CSR order ----------------
__global__ void k_scatter(const int* __restrict__ src, const int* __restrict__ dst,
                          const int* __restrict__ row_ptr, int* __restrict__ offs,
                          int* __restrict__ src_sorted, int e) {
    int i = blockIdx.x * 256 + threadIdx.x;
    if (i < e) {
        int d = dst[i];
        int pos = row_ptr[d] + atomicAdd(&offs[d], 1);
        src_sorted[pos] = src[i];
    }
}

// ---------------- per-layer dense transform ----------------
// h[n,32] = in[n,32] @ W[32,32]^T ; a[n, 2H] = {a_s[H], a_d[H]}
// block = 256 threads = 8 nodes x 32 output channels.
template <int H>
__global__ void k_transform(const float* __restrict__ in, const float* __restrict__ W,
                            const float* __restrict__ att_s, const float* __restrict__ att_d,
                            float* __restrict__ h, float* __restrict__ a, int n) {
    constexpr int C = 32 / H;
    __shared__ float Wl[32][33];   // +1 pad: lanes read Wl[o][k], o varies
    __shared__ float xs[8][32];    // broadcast reads, no pad needed
    int t = threadIdx.x;
    for (int i = t; i < 1024; i += 256) Wl[i >> 5][i & 31] = W[i];
    int nl = t >> 5, o = t & 31;
    int node = blockIdx.x * 8 + nl;
    xs[nl][o] = (node < n) ? in[node * 32 + o] : 0.f;
    __syncthreads();
    float acc = 0.f;
#pragma unroll
    for (int k = 0; k < 32; k++) acc = fmaf(xs[nl][k], Wl[o][k], acc);
    if (node < n) {
        h[node * 32 + o] = acc;
        float vs = acc * att_s[o];   // att flat [h'*C + c] == [o]
        float vd = acc * att_d[o];
#pragma unroll
        for (int m = C / 2; m >= 1; m >>= 1) {
            vs += __shfl_xor(vs, m, 64);
            vd += __shfl_xor(vd, m, 64);
        }
        if ((o % C) == 0) {
            int hh = o / C;
            a[node * 2 * H + hh] = vs;          // a_s
            a[node * 2 * H + H + hh] = vd;      // a_d
        }
    }
}

// ---------------- per-layer fused edge softmax + aggregation ----------------
// One wave per destination node. Pass A: softmax denominator (lane-per-edge,
// wave all-reduce). Pass B: 64 lanes = 2 edges x 32 channels; coalesced 128B
// h[src] row gathers; alpha recomputed broadcast-uniform per half-wave.
// EPI: 0 = bias only (layer3), 1 = layer1 epilogue, 2 = elu+clip (layer2).
template <int H, int EPI>
__global__ void k_edge(const int* __restrict__ row_ptr, const int* __restrict__ src_sorted,
                       const float* __restrict__ h, const float* __restrict__ a,
                       const float* __restrict__ bias, const float* __restrict__ ea,
                       float* __restrict__ out, int n, float slope) {
    constexpr int C = 32 / H;
    int wid = threadIdx.x >> 6;
    int lane = threadIdx.x & 63;
    int node = blockIdx.x * 4 + wid;
    if (node >= n) return;
    int beg = row_ptr[node];
    int end = row_ptr[node + 1];

    float ad[H];
#pragma unroll
    for (int hh = 0; hh < H; hh++) ad[hh] = a[node * 2 * H + H + hh];  // broadcast

    // ---- pass A: denominator ----
    float ds[H];
#pragma unroll
    for (int hh = 0; hh < H; hh++) ds[hh] = 0.f;
    for (int eidx = beg + lane; eidx < end; eidx += 64) {
        int s = src_sorted[eidx];
#pragma unroll
        for (int hh = 0; hh < H; hh++) {
            float l = a[s * 2 * H + hh] + ad[hh];
            l = (l > 0.f) ? l : l * slope;
            ds[hh] += __expf(l);
        }
    }
#pragma unroll
    for (int hh = 0; hh < H; hh++) {
        float v = ds[hh];
#pragma unroll
        for (int m = 32; m >= 1; m >>= 1) v += __shfl_xor(v, m, 64);
        ds[hh] = 1.f / (v + 1e-16f);   // inv denom, all lanes
    }

    // ---- pass B: weighted aggregation ----
    int c = lane & 31;
    int hd = c / C;
    int halfbase = (lane >> 5) << 5;   // 0 or 32
    float acc = 0.f;
    float invd = ds[hd];
    for (int base0 = beg; base0 < end; base0 += 64) {
        int ecount = end - base0;
        int myn = ecount - halfbase;
        if (myn > 32) myn = 32;
        int ebase = base0 + halfbase;
        for (int j = 0; j < myn; j++) {
            int s = src_sorted[ebase + j];                  // broadcast in half-wave
            float l = a[s * 2 * H + hd] + ad[hd];           // broadcast
            l = (l > 0.f) ? l : l * slope;
            float alpha = __expf(l) * invd;
            acc = fmaf(alpha, h[s * 32 + c], acc);          // coalesced 128B row
        }
    }
    acc += __shfl_xor(acc, 32, 64);

    if (lane < 32) {
        float val = acc + bias[c];
        if (EPI == 1) {
            float s0 = tanhf(ea[0]);
            if (s0 < 0.1f) s0 = 1.0f;
            val *= s0 * 1.05f;                          // h*scale, then h += 0.05*h
            val = (val > 0.f) ? val : expm1f(val);      // elu
            val = fminf(3.f, fmaxf(-3.f, val));         // clip
        } else if (EPI == 2) {
            val = (val > 0.f) ? val : expm1f(val);
            val = fminf(3.f, fmaxf(-3.f, val));
        }
        out[node * 32 + c] = val;
    }
}

// ---------------------------------------------------------------------------
extern "C" void kernel_launch(void* const* d_in, const int* in_sizes, int n_in,
                              void* d_out, int out_size, void* d_ws, size_t ws_size,
                              hipStream_t stream) {
    const float* x   = (const float*)d_in[0];
    const int*   ei  = (const int*)d_in[1];
    const float* W1  = (const float*)d_in[2];
    const float* as1 = (const float*)d_in[3];
    const float* ad1 = (const float*)d_in[4];
    const float* b1  = (const float*)d_in[5];
    const float* ea1 = (const float*)d_in[6];
    const float* W2  = (const float*)d_in[7];
    const float* as2 = (const float*)d_in[8];
    const float* ad2 = (const float*)d_in[9];
    const float* b2  = (const float*)d_in[10];
    const float* W3  = (const float*)d_in[11];
    const float* as3 = (const float*)d_in[12];
    const float* ad3 = (const float*)d_in[13];
    const float* b3  = (const float*)d_in[14];
    float* out = (float*)d_out;

    const int n = in_sizes[0] / 32;   // 100000
    const int e = in_sizes[1] / 2;    // 3200000
    const int* src = ei;
    const int* dst = ei + e;

    // workspace carve-up (256B aligned)
    char* w = (char*)d_ws;
    auto alloc = [&](size_t bytes) -> void* {
        void* p = (void*)w;
        w += (bytes + 255) & ~(size_t)255;
        return p;
    };
    float* h      = (float*)alloc((size_t)n * 32 * 4);
    float* a      = (float*)alloc((size_t)n * 4 * 4);
    float* bufA   = (float*)alloc((size_t)n * 32 * 4);
    float* bufB   = (float*)alloc((size_t)n * 32 * 4);
    int* row_ptr  = (int*)alloc((size_t)(n + 1) * 4);
    int* counts   = (int*)alloc((size_t)n * 4);
    int* exsc     = (int*)alloc((size_t)n * 4);
    int* bsums    = (int*)alloc(128 * 4);
    int* offs     = (int*)alloc((size_t)n * 4);
    int* src_sorted = (int*)alloc((size_t)e * 4);

    // ---- build CSR by dst ----
    hipMemsetAsync(counts, 0, (size_t)n * 4, stream);
    hipMemsetAsync(offs, 0, (size_t)n * 4, stream);
    k_hist<<<(e + 255) / 256, 256, 0, stream>>>(dst, counts, e);
    int nb = (n + 1023) / 1024;   // 98 <= 128
    k_scan1<<<nb, 1024, 0, stream>>>(counts, exsc, bsums, n);
    k_scan2<<<1, 128, 0, stream>>>(bsums, nb);
    k_scan3<<<nb, 1024, 0, stream>>>(exsc, bsums, row_ptr, n, e);
    k_scatter<<<(e + 255) / 256, 256, 0, stream>>>(src, dst, row_ptr, offs, src_sorted, e);

    const int tgrid = (n + 7) / 8;
    const int egrid = (n + 3) / 4;

    // ---- layer 1: H=2, C=16, neg_slope=0.01, epilogue scale+1.05+elu+clip ----
    k_transform<2><<<tgrid, 256, 0, stream>>>(x, W1, as1, ad1, h, a, n);
    k_edge<2, 1><<<egrid, 256, 0, stream>>>(row_ptr, src_sorted, h, a, b1, ea1, bufA, n, 0.01f);

    // ---- layer 2: H=2, C=16, neg_slope=0.2, epilogue elu+clip ----
    k_transform<2><<<tgrid, 256, 0, stream>>>(bufA, W2, as2, ad2, h, a, n);
    k_edge<2, 2><<<egrid, 256, 0, stream>>>(row_ptr, src_sorted, h, a, b2, nullptr, bufB, n, 0.2f);

    // ---- layer 3: H=1, C=32, neg_slope=0.2, epilogue bias only ----
    k_transform<1><<<tgrid, 256, 0, stream>>>(bufB, W3, as3, ad3, h, a, n);
    k_edge<1, 0><<<egrid, 256, 0, stream>>>(row_ptr, src_sorted, h, a, b3, nullptr, out, n, 0.2f);
}

// Round 2
// 770.512 us; speedup vs baseline: 1.6111x; 1.6111x over previous
//
#include <hip/hip_runtime.h>
#include <hip/hip_bf16.h>

// ---------------------------------------------------------------------------
// EnhancedRGCN (3-layer GAT), N=100000 nodes, E=3200000 edges, D=32.
// CSR-by-dst counting sort once per call; per layer: dense transform + fused
// edge kernel (softmax denom pass + aggregation + activation epilogue).
// Pass B gathers 8 h-rows per wave instruction (8 edges x 8 lanes x float4),
// 2-way unrolled (16 edges in flight). Edge src ids + softmax numerators are
// staged in LDS during pass A (same-wave reuse, no barrier). No float atomics,
// no segment-max (shift-invariant softmax, bounded logits).
// ---------------------------------------------------------------------------

// ---------------- sort: histogram ----------------
__global__ void k_hist(const int* __restrict__ dst, int* __restrict__ counts, int e) {
    int i = blockIdx.x * 256 + threadIdx.x;
    if (i < e) atomicAdd(&counts[dst[i]], 1);
}

// ---------------- sort: 3-kernel exclusive scan ----------------
__global__ void k_scan1(const int* __restrict__ counts, int* __restrict__ exsc,
                        int* __restrict__ bsums, int n) {
    __shared__ int tmp[1024];
    int t = threadIdx.x;
    int gid = blockIdx.x * 1024 + t;
    int v = (gid < n) ? counts[gid] : 0;
    tmp[t] = v;
    __syncthreads();
#pragma unroll
    for (int off = 1; off < 1024; off <<= 1) {
        int add = (t >= off) ? tmp[t - off] : 0;
        __syncthreads();
        tmp[t] += add;
        __syncthreads();
    }
    if (gid < n) exsc[gid] = tmp[t] - v;   // exclusive within block
    if (t == 1023) bsums[blockIdx.x] = tmp[1023];
}

__global__ void k_scan2(int* __restrict__ bsums, int nb) {
    __shared__ int tmp[128];
    int t = threadIdx.x;
    int v = (t < nb) ? bsums[t] : 0;
    tmp[t] = v;
    __syncthreads();
#pragma unroll
    for (int off = 1; off < 128; off <<= 1) {
        int add = (t >= off) ? tmp[t - off] : 0;
        __syncthreads();
        tmp[t] += add;
        __syncthreads();
    }
    if (t < nb) bsums[t] = tmp[t] - v;     // exclusive block offsets
}

// writes row_ptr AND a mutable cursor copy for the scatter kernel
__global__ void k_scan3(const int* __restrict__ exsc, const int* __restrict__ bsums,
                        int* __restrict__ row_ptr, int* __restrict__ cursor, int n, int e) {
    int gid = blockIdx.x * 1024 + threadIdx.x;
    if (gid < n) {
        int v = exsc[gid] + bsums[blockIdx.x];
        row_ptr[gid] = v;
        cursor[gid] = v;
    }
    if (gid == 0) row_ptr[n] = e;
}

// ---------------- sort: scatter src ids into CSR order ----------------
__global__ void k_scatter(const int* __restrict__ src, const int* __restrict__ dst,
                          int* __restrict__ cursor, int* __restrict__ src_sorted, int e) {
    int i = blockIdx.x * 256 + threadIdx.x;
    if (i < e) {
        int pos = atomicAdd(&cursor[dst[i]], 1);
        src_sorted[pos] = src[i];
    }
}

// ---------------- per-layer dense transform ----------------
// h[n,32] = in[n,32] @ W[32,32]^T ; a[n, 2H] = {a_s[H], a_d[H]}
// block = 256 threads = 8 nodes x 32 output channels.
template <int H>
__global__ void k_transform(const float* __restrict__ in, const float* __restrict__ W,
                            const float* __restrict__ att_s, const float* __restrict__ att_d,
                            float* __restrict__ h, float* __restrict__ a, int n) {
    constexpr int C = 32 / H;
    __shared__ float Wl[32][33];   // +1 pad: lanes read Wl[o][k], o varies
    __shared__ float xs[8][32];    // broadcast reads, no pad needed
    int t = threadIdx.x;
    for (int i = t; i < 1024; i += 256) Wl[i >> 5][i & 31] = W[i];
    int nl = t >> 5, o = t & 31;
    int node = blockIdx.x * 8 + nl;
    xs[nl][o] = (node < n) ? in[node * 32 + o] : 0.f;
    __syncthreads();
    float acc = 0.f;
#pragma unroll
    for (int k = 0; k < 32; k++) acc = fmaf(xs[nl][k], Wl[o][k], acc);
    if (node < n) {
        h[node * 32 + o] = acc;
        float vs = acc * att_s[o];   // att flat [h'*C + c] == [o]
        float vd = acc * att_d[o];
#pragma unroll
        for (int m = C / 2; m >= 1; m >>= 1) {
            vs += __shfl_xor(vs, m, 64);
            vd += __shfl_xor(vd, m, 64);
        }
        if ((o % C) == 0) {
            int hh = o / C;
            a[node * 2 * H + hh] = vs;          // a_s
            a[node * 2 * H + H + hh] = vd;      // a_d
        }
    }
}

// ---------------- per-layer fused edge softmax + aggregation ----------------
// One wave per destination node.
// Pass A: lane-per-edge softmax denominator + stash (src id, exp numerators)
//         in this wave's LDS slice (deg<=CAP fast path; slow path recomputes).
// Pass B: 64 lanes = 8 edges x 8 lanes; each lane loads float4 of h[src] ->
//         one wave instruction gathers 8 full 128B rows. 2-way unrolled (16
//         edges in flight). xor-shuffle reduction over edge slots.
// EPI: 0 = bias only (layer3), 1 = layer1 epilogue, 2 = elu+clip (layer2).
template <int H, int EPI>
__global__ void k_edge(const int* __restrict__ row_ptr, const int* __restrict__ src_sorted,
                       const float* __restrict__ h, const float* __restrict__ a,
                       const float* __restrict__ bias, const float* __restrict__ ea,
                       float* __restrict__ out, int n, float slope) {
    constexpr int CAP = 128;
    __shared__ int   lds_s[4][CAP];
    __shared__ float lds_ex[4][CAP * H];
    int wid = threadIdx.x >> 6;
    int lane = threadIdx.x & 63;
    int node = blockIdx.x * 4 + wid;
    if (node >= n) return;
    int beg = row_ptr[node];
    int end = row_ptr[node + 1];
    int deg = end - beg;

    float ad[H];
#pragma unroll
    for (int hh = 0; hh < H; hh++) ad[hh] = a[node * 2 * H + H + hh];  // broadcast

    // ---- pass A: denominator + LDS stash ----
    float ds[H];
#pragma unroll
    for (int hh = 0; hh < H; hh++) ds[hh] = 0.f;
    for (int idx = lane; idx < deg; idx += 64) {
        int s = src_sorted[beg + idx];
        if (H == 2) {
            float2 as2 = *(const float2*)(a + s * 4);
            float l0 = as2.x + ad[0]; l0 = (l0 > 0.f) ? l0 : l0 * slope;
            float l1 = as2.y + ad[1]; l1 = (l1 > 0.f) ? l1 : l1 * slope;
            float e0 = __expf(l0), e1 = __expf(l1);
            ds[0] += e0; ds[1] += e1;
            if (idx < CAP) {
                lds_s[wid][idx] = s;
                lds_ex[wid][idx * 2] = e0;
                lds_ex[wid][idx * 2 + 1] = e1;
            }
        } else {
            float av = a[s * 2];
            float l0 = av + ad[0]; l0 = (l0 > 0.f) ? l0 : l0 * slope;
            float e0 = __expf(l0);
            ds[0] += e0;
            if (idx < CAP) {
                lds_s[wid][idx] = s;
                lds_ex[wid][idx] = e0;
            }
        }
    }
#pragma unroll
    for (int hh = 0; hh < H; hh++) {
        float v = ds[hh];
#pragma unroll
        for (int m = 32; m >= 1; m >>= 1) v += __shfl_xor(v, m, 64);
        ds[hh] = 1.f / (v + 1e-16f);   // inv denom, all lanes
    }

    // ---- pass B: 8 edges x 8 lanes x float4, 2-way unrolled ----
    int e8 = lane >> 3;        // edge slot 0..7
    int l8 = lane & 7;         // channel quad 0..7
    int hd = (H == 2) ? (l8 >> 2) : 0;
    float invd = ds[hd];
    float adh = ad[hd];
    float4 acc = make_float4(0.f, 0.f, 0.f, 0.f);

    for (int base = 0; base < deg; base += 16) {
        int i0 = base + e8;
        int i1 = base + 8 + e8;
        int s0 = 0, s1 = 0;
        float al0 = 0.f, al1 = 0.f;
        if (i0 < deg) {
            if (i0 < CAP) {
                s0 = lds_s[wid][i0];
                al0 = lds_ex[wid][i0 * H + hd] * invd;
            } else {
                s0 = src_sorted[beg + i0];
                float l = a[s0 * 2 * H + hd] + adh;
                l = (l > 0.f) ? l : l * slope;
                al0 = __expf(l) * invd;
            }
        }
        if (i1 < deg) {
            if (i1 < CAP) {
                s1 = lds_s[wid][i1];
                al1 = lds_ex[wid][i1 * H + hd] * invd;
            } else {
                s1 = src_sorted[beg + i1];
                float l = a[s1 * 2 * H + hd] + adh;
                l = (l > 0.f) ? l : l * slope;
                al1 = __expf(l) * invd;
            }
        }
        float4 h0 = *(const float4*)(h + (size_t)s0 * 32 + l8 * 4);
        float4 h1 = *(const float4*)(h + (size_t)s1 * 32 + l8 * 4);
        acc.x = fmaf(al0, h0.x, acc.x);
        acc.y = fmaf(al0, h0.y, acc.y);
        acc.z = fmaf(al0, h0.z, acc.z);
        acc.w = fmaf(al0, h0.w, acc.w);
        acc.x = fmaf(al1, h1.x, acc.x);
        acc.y = fmaf(al1, h1.y, acc.y);
        acc.z = fmaf(al1, h1.z, acc.z);
        acc.w = fmaf(al1, h1.w, acc.w);
    }

    // reduce across the 8 edge slots (lane bits 3..5)
#pragma unroll
    for (int m = 8; m <= 32; m <<= 1) {
        acc.x += __shfl_xor(acc.x, m, 64);
        acc.y += __shfl_xor(acc.y, m, 64);
        acc.z += __shfl_xor(acc.z, m, 64);
        acc.w += __shfl_xor(acc.w, m, 64);
    }

    if (lane < 8) {
        float4 bv = *(const float4*)(bias + l8 * 4);
        float v[4] = {acc.x + bv.x, acc.y + bv.y, acc.z + bv.z, acc.w + bv.w};
        if (EPI == 1) {
            float s0 = tanhf(ea[0]);
            if (s0 < 0.1f) s0 = 1.0f;
            s0 *= 1.05f;                               // h*scale, then h += 0.05*h
#pragma unroll
            for (int k = 0; k < 4; k++) {
                float val = v[k] * s0;
                val = (val > 0.f) ? val : expm1f(val);  // elu
                v[k] = fminf(3.f, fmaxf(-3.f, val));    // clip
            }
        } else if (EPI == 2) {
#pragma unroll
            for (int k = 0; k < 4; k++) {
                float val = v[k];
                val = (val > 0.f) ? val : expm1f(val);
                v[k] = fminf(3.f, fmaxf(-3.f, val));
            }
        }
        float4 o4 = make_float4(v[0], v[1], v[2], v[3]);
        *(float4*)(out + (size_t)node * 32 + l8 * 4) = o4;
    }
}

// ---------------------------------------------------------------------------
extern "C" void kernel_launch(void* const* d_in, const int* in_sizes, int n_in,
                              void* d_out, int out_size, void* d_ws, size_t ws_size,
                              hipStream_t stream) {
    const float* x   = (const float*)d_in[0];
    const int*   ei  = (const int*)d_in[1];
    const float* W1  = (const float*)d_in[2];
    const float* as1 = (const float*)d_in[3];
    const float* ad1 = (const float*)d_in[4];
    const float* b1  = (const float*)d_in[5];
    const float* ea1 = (const float*)d_in[6];
    const float* W2  = (const float*)d_in[7];
    const float* as2 = (const float*)d_in[8];
    const float* ad2 = (const float*)d_in[9];
    const float* b2  = (const float*)d_in[10];
    const float* W3  = (const float*)d_in[11];
    const float* as3 = (const float*)d_in[12];
    const float* ad3 = (const float*)d_in[13];
    const float* b3  = (const float*)d_in[14];
    float* out = (float*)d_out;

    const int n = in_sizes[0] / 32;   // 100000
    const int e = in_sizes[1] / 2;    // 3200000
    const int* src = ei;
    const int* dst = ei + e;

    // workspace carve-up (256B aligned)
    char* w = (char*)d_ws;
    auto alloc = [&](size_t bytes) -> void* {
        void* p = (void*)w;
        w += (bytes + 255) & ~(size_t)255;
        return p;
    };
    float* h      = (float*)alloc((size_t)n * 32 * 4);
    float* a      = (float*)alloc((size_t)n * 4 * 4);
    float* bufA   = (float*)alloc((size_t)n * 32 * 4);
    float* bufB   = (float*)alloc((size_t)n * 32 * 4);
    int* row_ptr  = (int*)alloc((size_t)(n + 1) * 4);
    int* counts   = (int*)alloc((size_t)n * 4);
    int* exsc     = (int*)alloc((size_t)n * 4);
    int* bsums    = (int*)alloc(128 * 4);
    int* cursor   = (int*)alloc((size_t)n * 4);
    int* src_sorted = (int*)alloc((size_t)e * 4);

    // ---- build CSR by dst ----
    hipMemsetAsync(counts, 0, (size_t)n * 4, stream);
    k_hist<<<(e + 255) / 256, 256, 0, stream>>>(dst, counts, e);
    int nb = (n + 1023) / 1024;   // 98 <= 128
    k_scan1<<<nb, 1024, 0, stream>>>(counts, exsc, bsums, n);
    k_scan2<<<1, 128, 0, stream>>>(bsums, nb);
    k_scan3<<<nb, 1024, 0, stream>>>(exsc, bsums, row_ptr, cursor, n, e);
    k_scatter<<<(e + 255) / 256, 256, 0, stream>>>(src, dst, cursor, src_sorted, e);

    const int tgrid = (n + 7) / 8;
    const int egrid = (n + 3) / 4;

    // ---- layer 1: H=2, C=16, neg_slope=0.01, epilogue scale+1.05+elu+clip ----
    k_transform<2><<<tgrid, 256, 0, stream>>>(x, W1, as1, ad1, h, a, n);
    k_edge<2, 1><<<egrid, 256, 0, stream>>>(row_ptr, src_sorted, h, a, b1, ea1, bufA, n, 0.01f);

    // ---- layer 2: H=2, C=16, neg_slope=0.2, epilogue elu+clip ----
    k_transform<2><<<tgrid, 256, 0, stream>>>(bufA, W2, as2, ad2, h, a, n);
    k_edge<2, 2><<<egrid, 256, 0, stream>>>(row_ptr, src_sorted, h, a, b2, nullptr, bufB, n, 0.2f);

    // ---- layer 3: H=1, C=32, neg_slope=0.2, epilogue bias only ----
    k_transform<1><<<tgrid, 256, 0, stream>>>(bufB, W3, as3, ad3, h, a, n);
    k_edge<1, 0><<<egrid, 256, 0, stream>>>(row_ptr, src_sorted, h, a, b3, nullptr, out, n, 0.2f);
}

// Round 3
// 472.767 us; speedup vs baseline: 2.6257x; 1.6298x over previous
//
#include <hip/hip_runtime.h>
#include <hip/hip_bf16.h>

// ---------------------------------------------------------------------------
// EnhancedRGCN (3-layer GAT), N=100000 nodes, E=3200000 edges, D=32.
// CSR-by-dst via two-level radix binning (bucket = dst>>8, 256 nodes/bucket):
//   pass0 LDS-aggregated coarse histogram -> tiny scan -> pass1 bin edges into
//   bucket regions as packed uint32 (src<<8 | dst&255) -> pass2 per-bucket LDS
//   sort producing row_ptr + src_sorted with L2-resident scatter.
// Per layer: dense transform + fused edge kernel (softmax denom + aggregation
// + activation epilogue). No segment-max (shift-invariant softmax, bounded
// logits); no float atomics.
// ---------------------------------------------------------------------------

#define NPB 256   // nodes per bucket (dst>>8)

// ---------------- pass 0: coarse bucket histogram ----------------
__global__ void k_bhist(const int* __restrict__ dst, int* __restrict__ bucket_cnt,
                        int e, int nb) {
    __shared__ int h[512];
    int t = threadIdx.x;
    for (int i = t; i < nb; i += 256) h[i] = 0;
    __syncthreads();
    int base = blockIdx.x * 256 * 16;
    for (int k = 0; k < 16; k++) {
        int i = base + k * 256 + t;
        if (i < e) atomicAdd(&h[dst[i] >> 8], 1);
    }
    __syncthreads();
    for (int i = t; i < nb; i += 256)
        if (h[i]) atomicAdd(&bucket_cnt[i], h[i]);
}

// ---------------- tiny scan over buckets (one block, 512 threads) ----------
__global__ void k_bucketscan(const int* __restrict__ bucket_cnt, int* __restrict__ bucket_base,
                             int* __restrict__ bucket_cursor, int* __restrict__ row_ptr,
                             int n, int nb, int e) {
    __shared__ int tmp[512];
    int t = threadIdx.x;
    int v = (t < nb) ? bucket_cnt[t] : 0;
    tmp[t] = v;
    __syncthreads();
#pragma unroll
    for (int off = 1; off < 512; off <<= 1) {
        int add = (t >= off) ? tmp[t - off] : 0;
        __syncthreads();
        tmp[t] += add;
        __syncthreads();
    }
    int excl = tmp[t] - v;
    if (t < nb) {
        bucket_base[t] = excl;
        bucket_cursor[t] = excl;
    }
    if (t == 0) {
        bucket_base[nb] = e;
        row_ptr[n] = e;
    }
}

// ---------------- pass 1: bin edges into bucket regions ----------------
__global__ void k_bin(const int* __restrict__ src, const int* __restrict__ dst,
                      int* __restrict__ bucket_cursor, unsigned int* __restrict__ pairs,
                      int e, int nb) {
    const int EPT = 8;
    __shared__ int h[512];
    __shared__ int cbase[512];
    int t = threadIdx.x;
    for (int i = t; i < nb; i += 256) h[i] = 0;
    __syncthreads();
    int base = blockIdx.x * 256 * EPT;
    int bk[EPT], off[EPT];
    unsigned int pk[EPT];
#pragma unroll
    for (int k = 0; k < EPT; k++) {
        int i = base + k * 256 + t;
        if (i < e) {
            int d = dst[i];
            int b = d >> 8;
            bk[k] = b;
            pk[k] = ((unsigned int)src[i] << 8) | (unsigned int)(d & 255);
            off[k] = atomicAdd(&h[b], 1);
        } else bk[k] = -1;
    }
    __syncthreads();
    for (int i = t; i < nb; i += 256)
        cbase[i] = h[i] ? atomicAdd(&bucket_cursor[i], h[i]) : 0;
    __syncthreads();
#pragma unroll
    for (int k = 0; k < EPT; k++)
        if (bk[k] >= 0) pairs[cbase[bk[k]] + off[k]] = pk[k];
}

// ---------------- pass 2: per-bucket LDS sort -> row_ptr + src_sorted ------
__global__ void k_bucket_sort(const unsigned int* __restrict__ pairs,
                              const int* __restrict__ bucket_base,
                              int* __restrict__ row_ptr, int* __restrict__ src_sorted,
                              int n) {
    __shared__ int cnt[NPB];
    __shared__ int cur[NPB];
    int b = blockIdx.x;
    int t = threadIdx.x;
    int bbase = bucket_base[b];
    int bend = bucket_base[b + 1];
    int m = bend - bbase;
    cnt[t] = 0;
    __syncthreads();
    for (int i = t; i < m; i += 256)
        atomicAdd(&cnt[pairs[bbase + i] & 255], 1);
    __syncthreads();
    int v = cnt[t];
#pragma unroll
    for (int off = 1; off < NPB; off <<= 1) {
        int add = (t >= off) ? cnt[t - off] : 0;
        __syncthreads();
        cnt[t] += add;
        __syncthreads();
    }
    int excl = cnt[t] - v;
    int node = b * NPB + t;
    if (node < n) row_ptr[node] = bbase + excl;
    cur[t] = excl;
    __syncthreads();
    for (int i = t; i < m; i += 256) {
        unsigned int p = pairs[bbase + i];
        int off = atomicAdd(&cur[p & 255], 1);
        src_sorted[bbase + off] = (int)(p >> 8);
    }
}

// ---------------- per-layer dense transform ----------------
// h[n,32] = in[n,32] @ W[32,32]^T ; a[n, 2H] = {a_s[H], a_d[H]}
// block = 256 threads = 8 nodes x 32 output channels.
template <int H>
__global__ void k_transform(const float* __restrict__ in, const float* __restrict__ W,
                            const float* __restrict__ att_s, const float* __restrict__ att_d,
                            float* __restrict__ h, float* __restrict__ a, int n) {
    constexpr int C = 32 / H;
    __shared__ float Wl[32][33];   // +1 pad: lanes read Wl[o][k], o varies
    __shared__ float xs[8][32];    // broadcast reads, no pad needed
    int t = threadIdx.x;
    for (int i = t; i < 1024; i += 256) Wl[i >> 5][i & 31] = W[i];
    int nl = t >> 5, o = t & 31;
    int node = blockIdx.x * 8 + nl;
    xs[nl][o] = (node < n) ? in[node * 32 + o] : 0.f;
    __syncthreads();
    float acc = 0.f;
#pragma unroll
    for (int k = 0; k < 32; k++) acc = fmaf(xs[nl][k], Wl[o][k], acc);
    if (node < n) {
        h[node * 32 + o] = acc;
        float vs = acc * att_s[o];   // att flat [h'*C + c] == [o]
        float vd = acc * att_d[o];
#pragma unroll
        for (int m = C / 2; m >= 1; m >>= 1) {
            vs += __shfl_xor(vs, m, 64);
            vd += __shfl_xor(vd, m, 64);
        }
        if ((o % C) == 0) {
            int hh = o / C;
            a[node * 2 * H + hh] = vs;          // a_s
            a[node * 2 * H + H + hh] = vd;      // a_d
        }
    }
}

// ---------------- per-layer fused edge softmax + aggregation ----------------
// One wave per destination node.
// Pass A: lane-per-edge softmax denominator + stash (src id, exp numerators)
//         in this wave's LDS slice (deg<=CAP fast path; slow path recomputes).
// Pass B: 64 lanes = 8 edges x 8 lanes; each lane loads float4 of h[src] ->
//         one wave instruction gathers 8 full 128B rows. 2-way unrolled (16
//         edges in flight). xor-shuffle reduction over edge slots.
// EPI: 0 = bias only (layer3), 1 = layer1 epilogue, 2 = elu+clip (layer2).
template <int H, int EPI>
__global__ void k_edge(const int* __restrict__ row_ptr, const int* __restrict__ src_sorted,
                       const float* __restrict__ h, const float* __restrict__ a,
                       const float* __restrict__ bias, const float* __restrict__ ea,
                       float* __restrict__ out, int n, float slope) {
    constexpr int CAP = 128;
    __shared__ int   lds_s[4][CAP];
    __shared__ float lds_ex[4][CAP * H];
    int wid = threadIdx.x >> 6;
    int lane = threadIdx.x & 63;
    int node = blockIdx.x * 4 + wid;
    if (node >= n) return;
    int beg = row_ptr[node];
    int end = row_ptr[node + 1];
    int deg = end - beg;

    float ad[H];
#pragma unroll
    for (int hh = 0; hh < H; hh++) ad[hh] = a[node * 2 * H + H + hh];  // broadcast

    // ---- pass A: denominator + LDS stash ----
    float ds[H];
#pragma unroll
    for (int hh = 0; hh < H; hh++) ds[hh] = 0.f;
    for (int idx = lane; idx < deg; idx += 64) {
        int s = src_sorted[beg + idx];
        if (H == 2) {
            float2 as2 = *(const float2*)(a + s * 4);
            float l0 = as2.x + ad[0]; l0 = (l0 > 0.f) ? l0 : l0 * slope;
            float l1 = as2.y + ad[1]; l1 = (l1 > 0.f) ? l1 : l1 * slope;
            float e0 = __expf(l0), e1 = __expf(l1);
            ds[0] += e0; ds[1] += e1;
            if (idx < CAP) {
                lds_s[wid][idx] = s;
                lds_ex[wid][idx * 2] = e0;
                lds_ex[wid][idx * 2 + 1] = e1;
            }
        } else {
            float av = a[s * 2];
            float l0 = av + ad[0]; l0 = (l0 > 0.f) ? l0 : l0 * slope;
            float e0 = __expf(l0);
            ds[0] += e0;
            if (idx < CAP) {
                lds_s[wid][idx] = s;
                lds_ex[wid][idx] = e0;
            }
        }
    }
#pragma unroll
    for (int hh = 0; hh < H; hh++) {
        float v = ds[hh];
#pragma unroll
        for (int m = 32; m >= 1; m >>= 1) v += __shfl_xor(v, m, 64);
        ds[hh] = 1.f / (v + 1e-16f);   // inv denom, all lanes
    }

    // ---- pass B: 8 edges x 8 lanes x float4, 2-way unrolled ----
    int e8 = lane >> 3;        // edge slot 0..7
    int l8 = lane & 7;         // channel quad 0..7
    int hd = (H == 2) ? (l8 >> 2) : 0;
    float invd = ds[hd];
    float adh = ad[hd];
    float4 acc = make_float4(0.f, 0.f, 0.f, 0.f);

    for (int base = 0; base < deg; base += 16) {
        int i0 = base + e8;
        int i1 = base + 8 + e8;
        int s0 = 0, s1 = 0;
        float al0 = 0.f, al1 = 0.f;
        if (i0 < deg) {
            if (i0 < CAP) {
                s0 = lds_s[wid][i0];
                al0 = lds_ex[wid][i0 * H + hd] * invd;
            } else {
                s0 = src_sorted[beg + i0];
                float l = a[s0 * 2 * H + hd] + adh;
                l = (l > 0.f) ? l : l * slope;
                al0 = __expf(l) * invd;
            }
        }
        if (i1 < deg) {
            if (i1 < CAP) {
                s1 = lds_s[wid][i1];
                al1 = lds_ex[wid][i1 * H + hd] * invd;
            } else {
                s1 = src_sorted[beg + i1];
                float l = a[s1 * 2 * H + hd] + adh;
                l = (l > 0.f) ? l : l * slope;
                al1 = __expf(l) * invd;
            }
        }
        float4 h0 = *(const float4*)(h + (size_t)s0 * 32 + l8 * 4);
        float4 h1 = *(const float4*)(h + (size_t)s1 * 32 + l8 * 4);
        acc.x = fmaf(al0, h0.x, acc.x);
        acc.y = fmaf(al0, h0.y, acc.y);
        acc.z = fmaf(al0, h0.z, acc.z);
        acc.w = fmaf(al0, h0.w, acc.w);
        acc.x = fmaf(al1, h1.x, acc.x);
        acc.y = fmaf(al1, h1.y, acc.y);
        acc.z = fmaf(al1, h1.z, acc.z);
        acc.w = fmaf(al1, h1.w, acc.w);
    }

    // reduce across the 8 edge slots (lane bits 3..5)
#pragma unroll
    for (int m = 8; m <= 32; m <<= 1) {
        acc.x += __shfl_xor(acc.x, m, 64);
        acc.y += __shfl_xor(acc.y, m, 64);
        acc.z += __shfl_xor(acc.z, m, 64);
        acc.w += __shfl_xor(acc.w, m, 64);
    }

    if (lane < 8) {
        float4 bv = *(const float4*)(bias + l8 * 4);
        float v[4] = {acc.x + bv.x, acc.y + bv.y, acc.z + bv.z, acc.w + bv.w};
        if (EPI == 1) {
            float s0 = tanhf(ea[0]);
            if (s0 < 0.1f) s0 = 1.0f;
            s0 *= 1.05f;                               // h*scale, then h += 0.05*h
#pragma unroll
            for (int k = 0; k < 4; k++) {
                float val = v[k] * s0;
                val = (val > 0.f) ? val : expm1f(val);  // elu
                v[k] = fminf(3.f, fmaxf(-3.f, val));    // clip
            }
        } else if (EPI == 2) {
#pragma unroll
            for (int k = 0; k < 4; k++) {
                float val = v[k];
                val = (val > 0.f) ? val : expm1f(val);
                v[k] = fminf(3.f, fmaxf(-3.f, val));
            }
        }
        float4 o4 = make_float4(v[0], v[1], v[2], v[3]);
        *(float4*)(out + (size_t)node * 32 + l8 * 4) = o4;
    }
}

// ---------------------------------------------------------------------------
extern "C" void kernel_launch(void* const* d_in, const int* in_sizes, int n_in,
                              void* d_out, int out_size, void* d_ws, size_t ws_size,
                              hipStream_t stream) {
    const float* x   = (const float*)d_in[0];
    const int*   ei  = (const int*)d_in[1];
    const float* W1  = (const float*)d_in[2];
    const float* as1 = (const float*)d_in[3];
    const float* ad1 = (const float*)d_in[4];
    const float* b1  = (const float*)d_in[5];
    const float* ea1 = (const float*)d_in[6];
    const float* W2  = (const float*)d_in[7];
    const float* as2 = (const float*)d_in[8];
    const float* ad2 = (const float*)d_in[9];
    const float* b2  = (const float*)d_in[10];
    const float* W3  = (const float*)d_in[11];
    const float* as3 = (const float*)d_in[12];
    const float* ad3 = (const float*)d_in[13];
    const float* b3  = (const float*)d_in[14];
    float* out = (float*)d_out;

    const int n = in_sizes[0] / 32;   // 100000
    const int e = in_sizes[1] / 2;    // 3200000
    const int* src = ei;
    const int* dst = ei + e;
    const int nb = (n + NPB - 1) / NPB;   // 391 buckets

    // workspace carve-up (256B aligned)
    char* w = (char*)d_ws;
    auto alloc = [&](size_t bytes) -> void* {
        void* p = (void*)w;
        w += (bytes + 255) & ~(size_t)255;
        return p;
    };
    float* h        = (float*)alloc((size_t)n * 32 * 4);
    float* a        = (float*)alloc((size_t)n * 4 * 4);
    float* bufA     = (float*)alloc((size_t)n * 32 * 4);   // also aliased as pairs
    float* bufB     = (float*)alloc((size_t)n * 32 * 4);
    int* row_ptr    = (int*)alloc((size_t)(n + 1) * 4);
    int* bucket_cnt = (int*)alloc((size_t)(nb + 1) * 4);
    int* bucket_base= (int*)alloc((size_t)(nb + 1) * 4);
    int* bucket_cur = (int*)alloc((size_t)(nb + 1) * 4);
    int* src_sorted = (int*)alloc((size_t)e * 4);
    // pairs aliased onto bufA (e*4 == n*32*4 bytes; consumed before layer 1
    // writes bufA)
    unsigned int* pairs = (unsigned int*)bufA;

    // ---- build CSR by dst (two-level radix binning) ----
    hipMemsetAsync(bucket_cnt, 0, (size_t)nb * 4, stream);
    k_bhist<<<(e + 4095) / 4096, 256, 0, stream>>>(dst, bucket_cnt, e, nb);
    k_bucketscan<<<1, 512, 0, stream>>>(bucket_cnt, bucket_base, bucket_cur, row_ptr, n, nb, e);
    k_bin<<<(e + 2047) / 2048, 256, 0, stream>>>(src, dst, bucket_cur, pairs, e, nb);
    k_bucket_sort<<<nb, 256, 0, stream>>>(pairs, bucket_base, row_ptr, src_sorted, n);

    const int tgrid = (n + 7) / 8;
    const int egrid = (n + 3) / 4;

    // ---- layer 1: H=2, C=16, neg_slope=0.01, epilogue scale+1.05+elu+clip ----
    k_transform<2><<<tgrid, 256, 0, stream>>>(x, W1, as1, ad1, h, a, n);
    k_edge<2, 1><<<egrid, 256, 0, stream>>>(row_ptr, src_sorted, h, a, b1, ea1, bufA, n, 0.01f);

    // ---- layer 2: H=2, C=16, neg_slope=0.2, epilogue elu+clip ----
    k_transform<2><<<tgrid, 256, 0, stream>>>(bufA, W2, as2, ad2, h, a, n);
    k_edge<2, 2><<<egrid, 256, 0, stream>>>(row_ptr, src_sorted, h, a, b2, nullptr, bufB, n, 0.2f);

    // ---- layer 3: H=1, C=32, neg_slope=0.2, epilogue bias only ----
    k_transform<1><<<tgrid, 256, 0, stream>>>(bufB, W3, as3, ad3, h, a, n);
    k_edge<1, 0><<<egrid, 256, 0, stream>>>(row_ptr, src_sorted, h, a, b3, nullptr, out, n, 0.2f);
}

// Round 4
// 435.632 us; speedup vs baseline: 2.8495x; 1.0852x over previous
//
#include <hip/hip_runtime.h>
#include <hip/hip_bf16.h>
#include <hip/hip_fp16.h>

// ---------------------------------------------------------------------------
// EnhancedRGCN (3-layer GAT), N=100000 nodes, E=3200000 edges, D=32.
// CSR-by-dst via two-level radix binning (bucket = dst>>7, 128 nodes/bucket).
// Per layer: dense transform (fp32 in -> h16 fp16 rows + a_s/a_d attention
// scalars) + fused edge kernel (softmax denom + aggregation + epilogue).
// h gathered as fp16 (64B rows) to halve gather traffic; LDS edge stash is
// zero-padded to a multiple of 32 so the aggregation fast path has no
// per-element bounds checks. No segment-max (shift-invariant softmax,
// bounded logits); no float atomics.
// ---------------------------------------------------------------------------

#define NPB 128   // nodes per bucket (dst>>7)

// ---------------- pass 0: coarse bucket histogram (int4 loads) -------------
__global__ void k_bhist(const int* __restrict__ dst, int* __restrict__ bucket_cnt,
                        int e, int nb) {
    __shared__ int h[1024];
    int t = threadIdx.x;
    for (int i = t; i < nb; i += 256) h[i] = 0;
    __syncthreads();
    const int4* d4 = (const int4*)dst;
    int e4 = e >> 2;
    int base = blockIdx.x * 1024;
#pragma unroll
    for (int k = 0; k < 4; k++) {
        int i = base + k * 256 + t;
        if (i < e4) {
            int4 v = d4[i];
            atomicAdd(&h[v.x >> 7], 1);
            atomicAdd(&h[v.y >> 7], 1);
            atomicAdd(&h[v.z >> 7], 1);
            atomicAdd(&h[v.w >> 7], 1);
        }
    }
    if (blockIdx.x == 0 && t < (e & 3))
        atomicAdd(&bucket_cnt[dst[(e & ~3) + t] >> 7], 1);
    __syncthreads();
    for (int i = t; i < nb; i += 256)
        if (h[i]) atomicAdd(&bucket_cnt[i], h[i]);
}

// ---------------- tiny scan over buckets (one block, 1024 threads) ---------
__global__ void k_bucketscan(const int* __restrict__ bucket_cnt, int* __restrict__ bucket_base,
                             int* __restrict__ bucket_cursor, int* __restrict__ row_ptr,
                             int n, int nb, int e) {
    __shared__ int tmp[1024];
    int t = threadIdx.x;
    int v = (t < nb) ? bucket_cnt[t] : 0;
    tmp[t] = v;
    __syncthreads();
#pragma unroll
    for (int off = 1; off < 1024; off <<= 1) {
        int add = (t >= off) ? tmp[t - off] : 0;
        __syncthreads();
        tmp[t] += add;
        __syncthreads();
    }
    int excl = tmp[t] - v;
    if (t < nb) {
        bucket_base[t] = excl;
        bucket_cursor[t] = excl;
    }
    if (t == 0) {
        bucket_base[nb] = e;
        row_ptr[n] = e;
    }
}

// ---------------- pass 1: bin edges into bucket regions ----------------
__global__ void k_bin(const int* __restrict__ src, const int* __restrict__ dst,
                      int* __restrict__ bucket_cursor, unsigned int* __restrict__ pairs,
                      int e, int nb) {
    const int EPT = 16;
    __shared__ int h[1024];
    __shared__ int cbase[1024];
    int t = threadIdx.x;
    for (int i = t; i < nb; i += 256) h[i] = 0;
    __syncthreads();
    int base = blockIdx.x * 256 * EPT;
    int bk[EPT], off[EPT];
    unsigned int pk[EPT];
#pragma unroll
    for (int k = 0; k < EPT; k++) {
        int i = base + k * 256 + t;
        if (i < e) {
            int d = dst[i];
            int b = d >> 7;
            bk[k] = b;
            pk[k] = ((unsigned int)src[i] << 7) | (unsigned int)(d & 127);
            off[k] = atomicAdd(&h[b], 1);
        } else bk[k] = -1;
    }
    __syncthreads();
    for (int i = t; i < nb; i += 256)
        cbase[i] = h[i] ? atomicAdd(&bucket_cursor[i], h[i]) : 0;
    __syncthreads();
#pragma unroll
    for (int k = 0; k < EPT; k++)
        if (bk[k] >= 0) pairs[cbase[bk[k]] + off[k]] = pk[k];
}

// ---------------- pass 2: per-bucket LDS sort -> row_ptr + src_sorted ------
__global__ void k_bucket_sort(const unsigned int* __restrict__ pairs,
                              const int* __restrict__ bucket_base,
                              int* __restrict__ row_ptr, int* __restrict__ src_sorted,
                              int n) {
    __shared__ int cnt[NPB];
    __shared__ int cur[NPB];
    int b = blockIdx.x;
    int t = threadIdx.x;
    int bbase = bucket_base[b];
    int bend = bucket_base[b + 1];
    int m = bend - bbase;
    if (t < NPB) cnt[t] = 0;
    __syncthreads();
    for (int i = t; i < m; i += 256)
        atomicAdd(&cnt[pairs[bbase + i] & 127], 1);
    __syncthreads();
    int v = (t < NPB) ? cnt[t] : 0;
#pragma unroll
    for (int off = 1; off < NPB; off <<= 1) {
        int add = (t >= off && t < NPB) ? cnt[t - off] : 0;
        __syncthreads();
        if (t < NPB) cnt[t] += add;
        __syncthreads();
    }
    if (t < NPB) {
        int excl = cnt[t] - v;
        int node = b * NPB + t;
        if (node < n) row_ptr[node] = bbase + excl;
        cur[t] = excl;
    }
    __syncthreads();
    for (int i = t; i < m; i += 256) {
        unsigned int p = pairs[bbase + i];
        int off = atomicAdd(&cur[p & 127], 1);
        src_sorted[bbase + off] = (int)(p >> 7);
    }
}

// ---------------- per-layer dense transform ----------------
// h16[n,32] = fp16(in[n,32] @ W[32,32]^T); a_s/a_d[n,H] attention scalars.
// block = 256 threads = 8 nodes x 32 output channels.
template <int H>
__global__ void k_transform(const float* __restrict__ in, const float* __restrict__ W,
                            const float* __restrict__ att_s, const float* __restrict__ att_d,
                            __half* __restrict__ h16, float* __restrict__ a_s,
                            float* __restrict__ a_d, int n) {
    constexpr int C = 32 / H;
    __shared__ float Wl[32][33];   // +1 pad: lanes read Wl[o][k], o varies
    __shared__ float xs[8][32];    // broadcast reads, no pad needed
    int t = threadIdx.x;
    for (int i = t; i < 1024; i += 256) Wl[i >> 5][i & 31] = W[i];
    int nl = t >> 5, o = t & 31;
    int node = blockIdx.x * 8 + nl;
    xs[nl][o] = (node < n) ? in[node * 32 + o] : 0.f;
    __syncthreads();
    float acc = 0.f;
#pragma unroll
    for (int k = 0; k < 32; k++) acc = fmaf(xs[nl][k], Wl[o][k], acc);
    if (node < n) {
        h16[node * 32 + o] = __float2half_rn(acc);
        float vs = acc * att_s[o];   // att flat [h'*C + c] == [o]
        float vd = acc * att_d[o];
#pragma unroll
        for (int m = C / 2; m >= 1; m >>= 1) {
            vs += __shfl_xor(vs, m, 64);
            vd += __shfl_xor(vd, m, 64);
        }
        if ((o % C) == 0) {
            int hh = o / C;
            a_s[node * H + hh] = vs;
            a_d[node * H + hh] = vd;
        }
    }
}

// ---------------- per-layer fused edge softmax + aggregation ----------------
// One wave per destination node.
// Pass A: lane-per-edge softmax denominator; stash (src id, exp numerators)
//         in this wave's LDS slice, zero-padded to a multiple of 32 so pass B
//         needs no bounds checks (deg<=CAP fast path; slow path recomputes).
// Pass B: 64 lanes = 16 edges x 4 lanes; each lane loads 16B (8 fp16) of the
//         64B h16[src] row. 2-way unrolled (32 edges in flight). 4-level
//         xor-shuffle reduction over edge slots.
// EPI: 0 = bias only (layer3), 1 = layer1 epilogue, 2 = elu+clip (layer2).
template <int H, int EPI>
__global__ void k_edge(const int* __restrict__ row_ptr, const int* __restrict__ src_sorted,
                       const __half* __restrict__ h16,
                       const float* __restrict__ a_s, const float* __restrict__ a_d,
                       const float* __restrict__ bias, const float* __restrict__ ea,
                       float* __restrict__ out, int n, float slope) {
    constexpr int CAP = 160;                 // multiple of 32
    __shared__ int   lds_s[4][CAP];
    __shared__ float lds_ex[4][CAP * H];
    int wid = threadIdx.x >> 6;
    int lane = threadIdx.x & 63;
    int node = blockIdx.x * 4 + wid;
    if (node >= n) return;
    int beg = row_ptr[node];
    int deg = row_ptr[node + 1] - beg;
    int padded = (deg + 31) & ~31;

    float ad[H];
#pragma unroll
    for (int hh = 0; hh < H; hh++) ad[hh] = a_d[node * H + hh];  // broadcast

    // ---- pass A: denominator (+ padded LDS stash on fast path) ----
    float ds[H];
#pragma unroll
    for (int hh = 0; hh < H; hh++) ds[hh] = 0.f;
    if (padded <= CAP) {
        for (int idx = lane; idx < padded; idx += 64) {
            if (idx < deg) {
                int s = src_sorted[beg + idx];
                lds_s[wid][idx] = s;
                if (H == 2) {
                    float2 as2 = *(const float2*)(a_s + s * 2);
                    float l0 = as2.x + ad[0]; l0 = (l0 > 0.f) ? l0 : l0 * slope;
                    float l1 = as2.y + ad[1]; l1 = (l1 > 0.f) ? l1 : l1 * slope;
                    float e0 = __expf(l0), e1 = __expf(l1);
                    ds[0] += e0; ds[1] += e1;
                    lds_ex[wid][idx * 2] = e0;
                    lds_ex[wid][idx * 2 + 1] = e1;
                } else {
                    float l0 = a_s[s] + ad[0]; l0 = (l0 > 0.f) ? l0 : l0 * slope;
                    float e0 = __expf(l0);
                    ds[0] += e0;
                    lds_ex[wid][idx] = e0;
                }
            } else {
                lds_s[wid][idx] = 0;
#pragma unroll
                for (int hh = 0; hh < H; hh++) lds_ex[wid][idx * H + hh] = 0.f;
            }
        }
    } else {
        for (int idx = lane; idx < deg; idx += 64) {
            int s = src_sorted[beg + idx];
            if (H == 2) {
                float2 as2 = *(const float2*)(a_s + s * 2);
                float l0 = as2.x + ad[0]; l0 = (l0 > 0.f) ? l0 : l0 * slope;
                float l1 = as2.y + ad[1]; l1 = (l1 > 0.f) ? l1 : l1 * slope;
                ds[0] += __expf(l0); ds[1] += __expf(l1);
            } else {
                float l0 = a_s[s] + ad[0]; l0 = (l0 > 0.f) ? l0 : l0 * slope;
                ds[0] += __expf(l0);
            }
        }
    }
#pragma unroll
    for (int hh = 0; hh < H; hh++) {
        float v = ds[hh];
#pragma unroll
        for (int m = 32; m >= 1; m >>= 1) v += __shfl_xor(v, m, 64);
        ds[hh] = 1.f / (v + 1e-16f);   // inv denom, all lanes
    }

    // ---- pass B: 16 edges x 4 lanes x 16B (8 fp16), 2-way unrolled ----
    int e16 = lane >> 2;       // edge slot 0..15
    int l4 = lane & 3;         // 8-channel group 0..3
    int hd = (H == 2) ? (l4 >> 1) : 0;
    float invd = ds[hd];
    float adh = ad[hd];
    float acc[8];
#pragma unroll
    for (int k = 0; k < 8; k++) acc[k] = 0.f;

    const char* hb = (const char*)h16;
    int coff = l4 << 4;   // byte offset of this lane's 16B chunk in a 64B row

    if (padded <= CAP) {
        for (int base = 0; base < padded; base += 32) {
            int i0 = base + e16;
            int i1 = base + 16 + e16;
            int s0 = lds_s[wid][i0];
            float al0 = lds_ex[wid][i0 * H + hd] * invd;
            int s1 = lds_s[wid][i1];
            float al1 = lds_ex[wid][i1 * H + hd] * invd;
            float4 r0 = *(const float4*)(hb + ((size_t)s0 << 6) + coff);
            float4 r1 = *(const float4*)(hb + ((size_t)s1 << 6) + coff);
            const __half2* p0 = (const __half2*)&r0;
            const __half2* p1 = (const __half2*)&r1;
#pragma unroll
            for (int q = 0; q < 4; q++) {
                float2 f0 = __half22float2(p0[q]);
                float2 f1 = __half22float2(p1[q]);
                acc[q * 2]     = fmaf(al0, f0.x, acc[q * 2]);
                acc[q * 2 + 1] = fmaf(al0, f0.y, acc[q * 2 + 1]);
                acc[q * 2]     = fmaf(al1, f1.x, acc[q * 2]);
                acc[q * 2 + 1] = fmaf(al1, f1.y, acc[q * 2 + 1]);
            }
        }
    } else {
        for (int base = 0; base < deg; base += 32) {
            int i0 = base + e16;
            int i1 = base + 16 + e16;
            int s0 = 0, s1 = 0;
            float al0 = 0.f, al1 = 0.f;
            if (i0 < deg) {
                s0 = src_sorted[beg + i0];
                float l = a_s[s0 * H + hd] + adh;
                l = (l > 0.f) ? l : l * slope;
                al0 = __expf(l) * invd;
            }
            if (i1 < deg) {
                s1 = src_sorted[beg + i1];
                float l = a_s[s1 * H + hd] + adh;
                l = (l > 0.f) ? l : l * slope;
                al1 = __expf(l) * invd;
            }
            float4 r0 = *(const float4*)(hb + ((size_t)s0 << 6) + coff);
            float4 r1 = *(const float4*)(hb + ((size_t)s1 << 6) + coff);
            const __half2* p0 = (const __half2*)&r0;
            const __half2* p1 = (const __half2*)&r1;
#pragma unroll
            for (int q = 0; q < 4; q++) {
                float2 f0 = __half22float2(p0[q]);
                float2 f1 = __half22float2(p1[q]);
                acc[q * 2]     = fmaf(al0, f0.x, acc[q * 2]);
                acc[q * 2 + 1] = fmaf(al0, f0.y, acc[q * 2 + 1]);
                acc[q * 2]     = fmaf(al1, f1.x, acc[q * 2]);
                acc[q * 2 + 1] = fmaf(al1, f1.y, acc[q * 2 + 1]);
            }
        }
    }

    // reduce across the 16 edge slots (lane bits 2..5)
#pragma unroll
    for (int m = 4; m <= 32; m <<= 1)
#pragma unroll
        for (int k = 0; k < 8; k++) acc[k] += __shfl_xor(acc[k], m, 64);

    if (lane < 4) {
        float4 b0 = *(const float4*)(bias + l4 * 8);
        float4 b1 = *(const float4*)(bias + l4 * 8 + 4);
        float vo[8] = {acc[0] + b0.x, acc[1] + b0.y, acc[2] + b0.z, acc[3] + b0.w,
                       acc[4] + b1.x, acc[5] + b1.y, acc[6] + b1.z, acc[7] + b1.w};
        if (EPI == 1) {
            float s0 = tanhf(ea[0]);
            if (s0 < 0.1f) s0 = 1.0f;
            s0 *= 1.05f;                               // h*scale, then h += 0.05*h
#pragma unroll
            for (int k = 0; k < 8; k++) {
                float val = vo[k] * s0;
                val = (val > 0.f) ? val : expm1f(val);  // elu
                vo[k] = fminf(3.f, fmaxf(-3.f, val));   // clip
            }
        } else if (EPI == 2) {
#pragma unroll
            for (int k = 0; k < 8; k++) {
                float val = vo[k];
                val = (val > 0.f) ? val : expm1f(val);
                vo[k] = fminf(3.f, fmaxf(-3.f, val));
            }
        }
        float* op = out + (size_t)node * 32 + l4 * 8;
        *(float4*)op       = make_float4(vo[0], vo[1], vo[2], vo[3]);
        *(float4*)(op + 4) = make_float4(vo[4], vo[5], vo[6], vo[7]);
    }
}

// ---------------------------------------------------------------------------
extern "C" void kernel_launch(void* const* d_in, const int* in_sizes, int n_in,
                              void* d_out, int out_size, void* d_ws, size_t ws_size,
                              hipStream_t stream) {
    const float* x   = (const float*)d_in[0];
    const int*   ei  = (const int*)d_in[1];
    const float* W1  = (const float*)d_in[2];
    const float* as1 = (const float*)d_in[3];
    const float* ad1 = (const float*)d_in[4];
    const float* b1  = (const float*)d_in[5];
    const float* ea1 = (const float*)d_in[6];
    const float* W2  = (const float*)d_in[7];
    const float* as2 = (const float*)d_in[8];
    const float* ad2 = (const float*)d_in[9];
    const float* b2  = (const float*)d_in[10];
    const float* W3  = (const float*)d_in[11];
    const float* as3 = (const float*)d_in[12];
    const float* ad3 = (const float*)d_in[13];
    const float* b3  = (const float*)d_in[14];
    float* out = (float*)d_out;

    const int n = in_sizes[0] / 32;   // 100000
    const int e = in_sizes[1] / 2;    // 3200000
    const int* src = ei;
    const int* dst = ei + e;
    const int nb = (n + NPB - 1) / NPB;   // 782 buckets

    // workspace carve-up (256B aligned)
    char* w = (char*)d_ws;
    auto alloc = [&](size_t bytes) -> void* {
        void* p = (void*)w;
        w += (bytes + 255) & ~(size_t)255;
        return p;
    };
    __half* h16     = (__half*)alloc((size_t)n * 32 * 2);
    float* a_s      = (float*)alloc((size_t)n * 2 * 4);
    float* a_d      = (float*)alloc((size_t)n * 2 * 4);
    float* bufA     = (float*)alloc((size_t)n * 32 * 4);   // also aliased as pairs
    float* bufB     = (float*)alloc((size_t)n * 32 * 4);
    int* row_ptr    = (int*)alloc((size_t)(n + 1) * 4);
    int* bucket_cnt = (int*)alloc((size_t)(nb + 1) * 4);
    int* bucket_base= (int*)alloc((size_t)(nb + 1) * 4);
    int* bucket_cur = (int*)alloc((size_t)(nb + 1) * 4);
    int* src_sorted = (int*)alloc((size_t)e * 4);
    // pairs aliased onto bufA (e*4 == n*32*4 bytes; consumed before layer 1
    // writes bufA)
    unsigned int* pairs = (unsigned int*)bufA;

    // ---- build CSR by dst (two-level radix binning) ----
    hipMemsetAsync(bucket_cnt, 0, (size_t)nb * 4, stream);
    int e4 = e >> 2;
    k_bhist<<<(e4 + 1023) / 1024, 256, 0, stream>>>(dst, bucket_cnt, e, nb);
    k_bucketscan<<<1, 1024, 0, stream>>>(bucket_cnt, bucket_base, bucket_cur, row_ptr, n, nb, e);
    k_bin<<<(e + 4095) / 4096, 256, 0, stream>>>(src, dst, bucket_cur, pairs, e, nb);
    k_bucket_sort<<<nb, 256, 0, stream>>>(pairs, bucket_base, row_ptr, src_sorted, n);

    const int tgrid = (n + 7) / 8;
    const int egrid = (n + 3) / 4;

    // ---- layer 1: H=2, C=16, neg_slope=0.01, epilogue scale+1.05+elu+clip ----
    k_transform<2><<<tgrid, 256, 0, stream>>>(x, W1, as1, ad1, h16, a_s, a_d, n);
    k_edge<2, 1><<<egrid, 256, 0, stream>>>(row_ptr, src_sorted, h16, a_s, a_d, b1, ea1, bufA, n, 0.01f);

    // ---- layer 2: H=2, C=16, neg_slope=0.2, epilogue elu+clip ----
    k_transform<2><<<tgrid, 256, 0, stream>>>(bufA, W2, as2, ad2, h16, a_s, a_d, n);
    k_edge<2, 2><<<egrid, 256, 0, stream>>>(row_ptr, src_sorted, h16, a_s, a_d, b2, nullptr, bufB, n, 0.2f);

    // ---- layer 3: H=1, C=32, neg_slope=0.2, epilogue bias only ----
    k_transform<1><<<tgrid, 256, 0, stream>>>(bufB, W3, as3, ad3, h16, a_s, a_d, n);
    k_edge<1, 0><<<egrid, 256, 0, stream>>>(row_ptr, src_sorted, h16, a_s, a_d, b3, nullptr, out, n, 0.2f);
}

// Round 5
// 412.643 us; speedup vs baseline: 3.0083x; 1.0557x over previous
//
#include <hip/hip_runtime.h>
#include <hip/hip_bf16.h>
#include <hip/hip_fp16.h>

// ---------------------------------------------------------------------------
// EnhancedRGCN (3-layer GAT), N=100000 nodes, E=3200000 edges, D=32.
// CSR-by-dst via two-level radix binning (bucket = dst>>7, 128 nodes/bucket).
// Per layer: dense transform (fp32 in -> h16 fp16 rows + a_s/a_d attention
// scalars) + fused edge kernel (softmax numerators stashed in LDS, raw
// exp-weighted aggregation, single invd multiply in the epilogue).
// Pass B: 4 edges x 16 lanes x half2, 4-way unrolled, v_fma_mix accumulation,
// 2-shuffle-level reduction. No segment-max (shift-invariant softmax, bounded
// logits); no float atomics; leaky_relu(l) = max(l, l*slope) for slope<1.
// ---------------------------------------------------------------------------

#define NPB 128   // nodes per bucket (dst>>7)

// ---------------- pass 0: coarse bucket histogram (int4 loads) -------------
__global__ void k_bhist(const int* __restrict__ dst, int* __restrict__ bucket_cnt,
                        int e, int nb) {
    __shared__ int h[1024];
    int t = threadIdx.x;
    for (int i = t; i < nb; i += 256) h[i] = 0;
    __syncthreads();
    const int4* d4 = (const int4*)dst;
    int e4 = e >> 2;
    int base = blockIdx.x * 1024;
#pragma unroll
    for (int k = 0; k < 4; k++) {
        int i = base + k * 256 + t;
        if (i < e4) {
            int4 v = d4[i];
            atomicAdd(&h[v.x >> 7], 1);
            atomicAdd(&h[v.y >> 7], 1);
            atomicAdd(&h[v.z >> 7], 1);
            atomicAdd(&h[v.w >> 7], 1);
        }
    }
    if (blockIdx.x == 0 && t < (e & 3))
        atomicAdd(&bucket_cnt[dst[(e & ~3) + t] >> 7], 1);
    __syncthreads();
    for (int i = t; i < nb; i += 256)
        if (h[i]) atomicAdd(&bucket_cnt[i], h[i]);
}

// ---------------- bucket scan: ONE wave, shfl-based, zero barriers ---------
__global__ void k_bucketscan(const int* __restrict__ bucket_cnt, int* __restrict__ bucket_base,
                             int* __restrict__ bucket_cursor, int* __restrict__ row_ptr,
                             int n, int nb, int e) {
    int lane = threadIdx.x;           // 64 threads
    int per = (nb + 63) >> 6;         // elems per lane (<=16 for nb<=1024)
    int vals[16];
    int base = lane * per;
    int sum = 0;
#pragma unroll 4
    for (int k = 0; k < per; k++) {
        int i = base + k;
        int c = (i < nb) ? bucket_cnt[i] : 0;
        vals[k] = sum;                // exclusive within lane
        sum += c;
    }
    int run = sum;
#pragma unroll
    for (int off = 1; off < 64; off <<= 1) {
        int v = __shfl_up(run, off, 64);
        if (lane >= off) run += v;
    }
    int lane_base = run - sum;        // exclusive across lanes
#pragma unroll 4
    for (int k = 0; k < per; k++) {
        int i = base + k;
        if (i < nb) {
            int v = lane_base + vals[k];
            bucket_base[i] = v;
            bucket_cursor[i] = v;
        }
    }
    if (lane == 0) {
        bucket_base[nb] = e;
        row_ptr[n] = e;
    }
}

// ---------------- pass 1: bin edges into bucket regions ----------------
__global__ void k_bin(const int* __restrict__ src, const int* __restrict__ dst,
                      int* __restrict__ bucket_cursor, unsigned int* __restrict__ pairs,
                      int e, int nb) {
    const int EPT = 16;
    __shared__ int h[1024];
    __shared__ int cbase[1024];
    int t = threadIdx.x;
    for (int i = t; i < nb; i += 256) h[i] = 0;
    __syncthreads();
    int base = blockIdx.x * 256 * EPT;
    int bk[EPT], off[EPT];
    unsigned int pk[EPT];
#pragma unroll
    for (int k = 0; k < EPT; k++) {
        int i = base + k * 256 + t;
        if (i < e) {
            int d = dst[i];
            int b = d >> 7;
            bk[k] = b;
            pk[k] = ((unsigned int)src[i] << 7) | (unsigned int)(d & 127);
            off[k] = atomicAdd(&h[b], 1);
        } else bk[k] = -1;
    }
    __syncthreads();
    for (int i = t; i < nb; i += 256)
        cbase[i] = h[i] ? atomicAdd(&bucket_cursor[i], h[i]) : 0;
    __syncthreads();
#pragma unroll
    for (int k = 0; k < EPT; k++)
        if (bk[k] >= 0) pairs[cbase[bk[k]] + off[k]] = pk[k];
}

// ---------------- pass 2: per-bucket LDS sort -> row_ptr + src_sorted ------
// 128-bin scan done by wave 0 via shfl (2 barriers total).
__global__ void k_bucket_sort(const unsigned int* __restrict__ pairs,
                              const int* __restrict__ bucket_base,
                              int* __restrict__ row_ptr, int* __restrict__ src_sorted,
                              int n) {
    __shared__ int cnt[NPB];
    __shared__ int cur[NPB];
    int b = blockIdx.x;
    int t = threadIdx.x;
    int bbase = bucket_base[b];
    int bend = bucket_base[b + 1];
    int m = bend - bbase;
    if (t < NPB) cnt[t] = 0;
    __syncthreads();
    for (int i = t; i < m; i += 256)
        atomicAdd(&cnt[pairs[bbase + i] & 127], 1);
    __syncthreads();
    if (t < 64) {                       // wave 0 only: shfl scan over 128 bins
        int c0 = cnt[2 * t];
        int c1 = cnt[2 * t + 1];
        int sum = c0 + c1;
        int run = sum;
#pragma unroll
        for (int off = 1; off < 64; off <<= 1) {
            int v = __shfl_up(run, off, 64);
            if (t >= off) run += v;
        }
        int ex = run - sum;             // exclusive
        cur[2 * t] = ex;
        cur[2 * t + 1] = ex + c0;
        int node = b * NPB + 2 * t;
        if (node < n) row_ptr[node] = bbase + ex;
        if (node + 1 < n) row_ptr[node + 1] = bbase + ex + c0;
    }
    __syncthreads();
    for (int i = t; i < m; i += 256) {
        unsigned int p = pairs[bbase + i];
        int off = atomicAdd(&cur[p & 127], 1);
        src_sorted[bbase + off] = (int)(p >> 7);
    }
}

// ---------------- per-layer dense transform ----------------
// h16[n,32] = fp16(in[n,32] @ W[32,32]^T); a_s/a_d[n,H] attention scalars.
// block = 256 threads = 8 nodes x 32 output channels.
template <int H>
__global__ void k_transform(const float* __restrict__ in, const float* __restrict__ W,
                            const float* __restrict__ att_s, const float* __restrict__ att_d,
                            __half* __restrict__ h16, float* __restrict__ a_s,
                            float* __restrict__ a_d, int n) {
    constexpr int C = 32 / H;
    __shared__ float Wl[32][33];   // +1 pad: lanes read Wl[o][k], o varies
    __shared__ float xs[8][32];    // broadcast reads, no pad needed
    int t = threadIdx.x;
    for (int i = t; i < 1024; i += 256) Wl[i >> 5][i & 31] = W[i];
    int nl = t >> 5, o = t & 31;
    int node = blockIdx.x * 8 + nl;
    xs[nl][o] = (node < n) ? in[node * 32 + o] : 0.f;
    __syncthreads();
    float acc = 0.f;
#pragma unroll
    for (int k = 0; k < 32; k++) acc = fmaf(xs[nl][k], Wl[o][k], acc);
    if (node < n) {
        h16[node * 32 + o] = __float2half_rn(acc);
        float vs = acc * att_s[o];   // att flat [h'*C + c] == [o]
        float vd = acc * att_d[o];
#pragma unroll
        for (int m = C / 2; m >= 1; m >>= 1) {
            vs += __shfl_xor(vs, m, 64);
            vd += __shfl_xor(vd, m, 64);
        }
        if ((o % C) == 0) {
            int hh = o / C;
            a_s[node * H + hh] = vs;
            a_d[node * H + hh] = vd;
        }
    }
}

// ---------------- per-layer fused edge softmax + aggregation ----------------
// One wave per destination node, no barriers (per-wave LDS slices).
// Pass A: lane-per-edge: stash (src id, exp numerators) zero-padded to a
//         multiple of 16; accumulate denominator partials.
// Pass B: 64 lanes = 4 edges x 16 lanes; each lane loads half2 (2 ch) of the
//         64B h16 row; 4-way unrolled (16 edges in flight); raw exp-weighted
//         accumulation (invd applied once in epilogue); 2-level reduction.
// EPI: 0 = bias only (layer3), 1 = layer1 epilogue, 2 = elu+clip (layer2).
template <int H, int EPI>
__global__ void k_edge(const int* __restrict__ row_ptr, const int* __restrict__ src_sorted,
                       const __half* __restrict__ h16,
                       const float* __restrict__ a_s, const float* __restrict__ a_d,
                       const float* __restrict__ bias, const float* __restrict__ ea,
                       float* __restrict__ out, int n, float slope) {
    constexpr int CAP = 160;                 // multiple of 16
    __shared__ int   lds_s[4][CAP];
    __shared__ float lds_ex[4][CAP * H];
    int wid = threadIdx.x >> 6;
    int lane = threadIdx.x & 63;
    int node = blockIdx.x * 4 + wid;
    if (node >= n) return;
    int beg = row_ptr[node];
    int deg = row_ptr[node + 1] - beg;
    int padded = (deg + 15) & ~15;

    float ad[H];
#pragma unroll
    for (int hh = 0; hh < H; hh++) ad[hh] = a_d[node * H + hh];  // broadcast

    // ---- pass A: stash numerators + denominator partials ----
    float ds[H];
#pragma unroll
    for (int hh = 0; hh < H; hh++) ds[hh] = 0.f;
    bool fast = (padded <= CAP);
    if (fast) {
        for (int idx = lane; idx < padded; idx += 64) {
            if (idx < deg) {
                int s = src_sorted[beg + idx];
                lds_s[wid][idx] = s;
                if (H == 2) {
                    float2 as2 = *(const float2*)(a_s + s * 2);
                    float l0 = as2.x + ad[0]; l0 = fmaxf(l0, l0 * slope);
                    float l1 = as2.y + ad[1]; l1 = fmaxf(l1, l1 * slope);
                    float e0 = __expf(l0), e1 = __expf(l1);
                    ds[0] += e0; ds[1] += e1;
                    lds_ex[wid][idx * 2] = e0;
                    lds_ex[wid][idx * 2 + 1] = e1;
                } else {
                    float l0 = a_s[s] + ad[0]; l0 = fmaxf(l0, l0 * slope);
                    float e0 = __expf(l0);
                    ds[0] += e0;
                    lds_ex[wid][idx] = e0;
                }
            } else {
                lds_s[wid][idx] = 0;
#pragma unroll
                for (int hh = 0; hh < H; hh++) lds_ex[wid][idx * H + hh] = 0.f;
            }
        }
    } else {
        for (int idx = lane; idx < deg; idx += 64) {
            int s = src_sorted[beg + idx];
            if (H == 2) {
                float2 as2 = *(const float2*)(a_s + s * 2);
                float l0 = as2.x + ad[0]; l0 = fmaxf(l0, l0 * slope);
                float l1 = as2.y + ad[1]; l1 = fmaxf(l1, l1 * slope);
                ds[0] += __expf(l0); ds[1] += __expf(l1);
            } else {
                float l0 = a_s[s] + ad[0]; l0 = fmaxf(l0, l0 * slope);
                ds[0] += __expf(l0);
            }
        }
    }
#pragma unroll
    for (int hh = 0; hh < H; hh++) {
        float v = ds[hh];
#pragma unroll
        for (int m = 32; m >= 1; m >>= 1) v += __shfl_xor(v, m, 64);
        ds[hh] = 1.f / (v + 1e-16f);   // inv denom, all lanes
    }

    // ---- pass B: 4 edges x 16 lanes x half2, 4-way unrolled ----
    int e4 = lane >> 4;        // edge slot 0..3
    int l16 = lane & 15;       // channel pair 0..15
    int hd = (H == 2) ? (l16 >> 3) : 0;
    float adh = ad[hd];
    float acc0 = 0.f, acc1 = 0.f;
    const char* hb = (const char*)h16;
    int coff = l16 << 2;       // byte offset of this lane's half2 in a 64B row

    if (fast) {
        for (int base = 0; base < padded; base += 16) {
#pragma unroll
            for (int u = 0; u < 4; u++) {
                int idx = base + u * 4 + e4;
                int s = lds_s[wid][idx];
                float ex = lds_ex[wid][idx * H + hd];
                __half2 hv = *(const __half2*)(hb + ((size_t)s << 6) + coff);
                acc0 = fmaf(ex, __half2float(__low2half(hv)), acc0);
                acc1 = fmaf(ex, __half2float(__high2half(hv)), acc1);
            }
        }
    } else {
        for (int base = 0; base < deg; base += 16) {
#pragma unroll
            for (int u = 0; u < 4; u++) {
                int idx = base + u * 4 + e4;
                int s = 0;
                float ex = 0.f;
                if (idx < deg) {
                    s = src_sorted[beg + idx];
                    float l = a_s[s * H + hd] + adh;
                    l = fmaxf(l, l * slope);
                    ex = __expf(l);
                }
                __half2 hv = *(const __half2*)(hb + ((size_t)s << 6) + coff);
                acc0 = fmaf(ex, __half2float(__low2half(hv)), acc0);
                acc1 = fmaf(ex, __half2float(__high2half(hv)), acc1);
            }
        }
    }

    // reduce across the 4 edge slots (lane bits 4..5)
#pragma unroll
    for (int m = 16; m <= 32; m <<= 1) {
        acc0 += __shfl_xor(acc0, m, 64);
        acc1 += __shfl_xor(acc1, m, 64);
    }

    if (lane < 16) {
        float invd = ds[hd];
        float2 bv = *(const float2*)(bias + l16 * 2);
        float v0 = fmaf(acc0, invd, bv.x);
        float v1 = fmaf(acc1, invd, bv.y);
        if (EPI == 1) {
            float s0 = tanhf(ea[0]);
            if (s0 < 0.1f) s0 = 1.0f;
            s0 *= 1.05f;                               // h*scale, then h += 0.05*h
            v0 *= s0; v1 *= s0;
            v0 = (v0 > 0.f) ? v0 : expm1f(v0);         // elu
            v1 = (v1 > 0.f) ? v1 : expm1f(v1);
            v0 = fminf(3.f, fmaxf(-3.f, v0));          // clip
            v1 = fminf(3.f, fmaxf(-3.f, v1));
        } else if (EPI == 2) {
            v0 = (v0 > 0.f) ? v0 : expm1f(v0);
            v1 = (v1 > 0.f) ? v1 : expm1f(v1);
            v0 = fminf(3.f, fmaxf(-3.f, v0));
            v1 = fminf(3.f, fmaxf(-3.f, v1));
        }
        *(float2*)(out + (size_t)node * 32 + l16 * 2) = make_float2(v0, v1);
    }
}

// ---------------------------------------------------------------------------
extern "C" void kernel_launch(void* const* d_in, const int* in_sizes, int n_in,
                              void* d_out, int out_size, void* d_ws, size_t ws_size,
                              hipStream_t stream) {
    const float* x   = (const float*)d_in[0];
    const int*   ei  = (const int*)d_in[1];
    const float* W1  = (const float*)d_in[2];
    const float* as1 = (const float*)d_in[3];
    const float* ad1 = (const float*)d_in[4];
    const float* b1  = (const float*)d_in[5];
    const float* ea1 = (const float*)d_in[6];
    const float* W2  = (const float*)d_in[7];
    const float* as2 = (const float*)d_in[8];
    const float* ad2 = (const float*)d_in[9];
    const float* b2  = (const float*)d_in[10];
    const float* W3  = (const float*)d_in[11];
    const float* as3 = (const float*)d_in[12];
    const float* ad3 = (const float*)d_in[13];
    const float* b3  = (const float*)d_in[14];
    float* out = (float*)d_out;

    const int n = in_sizes[0] / 32;   // 100000
    const int e = in_sizes[1] / 2;    // 3200000
    const int* src = ei;
    const int* dst = ei + e;
    const int nb = (n + NPB - 1) / NPB;   // 782 buckets

    // workspace carve-up (256B aligned)
    char* w = (char*)d_ws;
    auto alloc = [&](size_t bytes) -> void* {
        void* p = (void*)w;
        w += (bytes + 255) & ~(size_t)255;
        return p;
    };
    __half* h16     = (__half*)alloc((size_t)n * 32 * 2);
    float* a_s      = (float*)alloc((size_t)n * 2 * 4);
    float* a_d      = (float*)alloc((size_t)n * 2 * 4);
    float* bufA     = (float*)alloc((size_t)n * 32 * 4);   // also aliased as pairs
    float* bufB     = (float*)alloc((size_t)n * 32 * 4);
    int* row_ptr    = (int*)alloc((size_t)(n + 1) * 4);
    int* bucket_cnt = (int*)alloc((size_t)(nb + 1) * 4);
    int* bucket_base= (int*)alloc((size_t)(nb + 1) * 4);
    int* bucket_cur = (int*)alloc((size_t)(nb + 1) * 4);
    int* src_sorted = (int*)alloc((size_t)e * 4);
    // pairs aliased onto bufA (e*4 == n*32*4 bytes; consumed before layer 1
    // writes bufA)
    unsigned int* pairs = (unsigned int*)bufA;

    // ---- build CSR by dst (two-level radix binning) ----
    hipMemsetAsync(bucket_cnt, 0, (size_t)nb * 4, stream);
    int e4 = e >> 2;
    k_bhist<<<(e4 + 1023) / 1024, 256, 0, stream>>>(dst, bucket_cnt, e, nb);
    k_bucketscan<<<1, 64, 0, stream>>>(bucket_cnt, bucket_base, bucket_cur, row_ptr, n, nb, e);
    k_bin<<<(e + 4095) / 4096, 256, 0, stream>>>(src, dst, bucket_cur, pairs, e, nb);
    k_bucket_sort<<<nb, 256, 0, stream>>>(pairs, bucket_base, row_ptr, src_sorted, n);

    const int tgrid = (n + 7) / 8;
    const int egrid = (n + 3) / 4;

    // ---- layer 1: H=2, C=16, neg_slope=0.01, epilogue scale+1.05+elu+clip ----
    k_transform<2><<<tgrid, 256, 0, stream>>>(x, W1, as1, ad1, h16, a_s, a_d, n);
    k_edge<2, 1><<<egrid, 256, 0, stream>>>(row_ptr, src_sorted, h16, a_s, a_d, b1, ea1, bufA, n, 0.01f);

    // ---- layer 2: H=2, C=16, neg_slope=0.2, epilogue elu+clip ----
    k_transform<2><<<tgrid, 256, 0, stream>>>(bufA, W2, as2, ad2, h16, a_s, a_d, n);
    k_edge<2, 2><<<egrid, 256, 0, stream>>>(row_ptr, src_sorted, h16, a_s, a_d, b2, nullptr, bufB, n, 0.2f);

    // ---- layer 3: H=1, C=32, neg_slope=0.2, epilogue bias only ----
    k_transform<1><<<tgrid, 256, 0, stream>>>(bufB, W3, as3, ad3, h16, a_s, a_d, n);
    k_edge<1, 0><<<egrid, 256, 0, stream>>>(row_ptr, src_sorted, h16, a_s, a_d, b3, nullptr, out, n, 0.2f);
}